// Round 1
// baseline (524.685 us; speedup 1.0000x reference)
//
#include <hip/hip_runtime.h>
#include <hip/hip_bf16.h>

#define BH 32      // bs*h
#define L  1024    // qlen == slen
#define D  64      // head dim
#define QT 16      // q rows per block

typedef __bf16 bf16x8 __attribute__((ext_vector_type(8)));
typedef float  f32x4  __attribute__((ext_vector_type(4)));

// ---------------------------------------------------------------------------
// Prep: q -> bf16 (same layout); k [bh][d][s] -> ktb [bh][s][d] bf16;
//       v [bh][s][d] -> vtb [bh][d][s] bf16.
// blocks 0..1023: q convert; 1024..1151: k transpose; 1152..1279: v transpose
// ---------------------------------------------------------------------------
__global__ __launch_bounds__(256) void prep_kernel(
    const float* __restrict__ q, const float* __restrict__ k,
    const float* __restrict__ v,
    __bf16* __restrict__ qb, __bf16* __restrict__ ktb, __bf16* __restrict__ vtb)
{
  __shared__ __align__(16) __bf16 T[256 * 66];  // 33792 B; also viewed as [64][258]
  const int tid = threadIdx.x;
  const int b = blockIdx.x;

  if (b < 1024) {
    // q convert: 8 contiguous elements per thread
    const size_t g = (size_t)b * 256 + tid;
    const float4* qin = (const float4*)q;
    float4 f0 = qin[g * 2];
    float4 f1 = qin[g * 2 + 1];
    union { bf16x8 v8; uint4 u4; } o;
    o.v8[0] = (__bf16)f0.x; o.v8[1] = (__bf16)f0.y;
    o.v8[2] = (__bf16)f0.z; o.v8[3] = (__bf16)f0.w;
    o.v8[4] = (__bf16)f1.x; o.v8[5] = (__bf16)f1.y;
    o.v8[6] = (__bf16)f1.z; o.v8[7] = (__bf16)f1.w;
    *(uint4*)(qb + g * 8) = o.u4;
  } else if (b < 1152) {
    // k transpose: [d][s] -> [s][d], 256-s chunk per block
    const int bb = b - 1024;
    const int bh = bb >> 2, chunk = bb & 3;
    const int s0 = chunk << 8;
    const float* kin = k + (size_t)bh * D * L;
    #pragma unroll
    for (int d = 0; d < 64; ++d)            // coalesced reads along s
      T[tid * 66 + d] = (__bf16)kin[(size_t)d * L + s0 + tid];
    __syncthreads();
    unsigned int* outw = (unsigned int*)ktb;
    const size_t obase = ((size_t)bh * L * D + (size_t)s0 * D) >> 1;  // dword idx
    #pragma unroll
    for (int j = 0; j < 32; ++j) {          // fully coalesced contiguous writes
      const int i = j * 256 + tid;
      const int s = i >> 5, dp = i & 31;
      outw[obase + i] = *(const unsigned int*)&T[s * 66 + dp * 2];
    }
  } else {
    // v transpose: [s][d] -> [d][s], 256-s chunk per block
    const int bb = b - 1152;
    const int bh = bb >> 2, chunk = bb & 3;
    const int s0 = chunk << 8;
    const float* vin = v + (size_t)bh * L * D + (size_t)s0 * D;
    #pragma unroll
    for (int jj = 0; jj < 64; ++jj) {       // coalesced reads
      const int e = jj * 256 + tid;
      const int s = e >> 6, d = e & 63;
      T[d * 258 + s] = (__bf16)vin[e];
    }
    __syncthreads();
    unsigned int* outw = (unsigned int*)vtb;
    #pragma unroll
    for (int j = 0; j < 32; ++j) {
      const int i = j * 256 + tid;
      const int d = i >> 7, sp = i & 127;
      outw[(size_t)bh * (L * D / 2) + (size_t)d * (L / 2) + (s0 >> 1) + sp] =
          *(const unsigned int*)&T[d * 258 + sp * 2];
    }
  }
}

// ---------------------------------------------------------------------------
// Main fused kernel: one block per (bh, 16-q-row tile); 4 waves, each owns a
// 256-wide s-chunk. MFMA 16x16x32 bf16 for QK^T and PV; softmax in fp32 held
// in the MFMA accumulator registers.
// ---------------------------------------------------------------------------
__global__ __launch_bounds__(256) void attn_kernel(
    const __bf16* __restrict__ qb, const __bf16* __restrict__ ktb,
    const __bf16* __restrict__ vtb,
    const float* __restrict__ prev, const float* __restrict__ scale_p,
    float* __restrict__ out_o, float* __restrict__ out_w,
    float* __restrict__ out_s)
{
  // P-stage: per wave [16 rows][280 cols] bf16 (pad 256->280: 2-way-only bank
  // aliasing on the b128 A-frag reads). Aliased with the O cross-wave
  // reduction buffer (16 KB) -- separated by __syncthreads.
  __shared__ __align__(16) char smem[4 * 16 * 280 * 2];  // 35840 B
  __shared__ float red_m[4][16];
  __shared__ float red_s[4][16];
  __bf16* w_stage = (__bf16*)smem;
  float*  o_red   = (float*)smem;

  const int tid  = threadIdx.x;
  const int wv   = tid >> 6;
  const int lane = tid & 63;
  const int quad = lane >> 4;
  const int l16  = lane & 15;
  const int bh   = blockIdx.x >> 6;
  const int qt   = blockIdx.x & 63;
  const float scale = scale_p[0];

  // A fragments (q tile rows), read straight from global (L2-hot)
  const __bf16* qtile = qb + ((size_t)bh * L + qt * QT) * D;
  const bf16x8 a0 = *(const bf16x8*)(qtile + l16 * D + quad * 8);
  const bf16x8 a1 = *(const bf16x8*)(qtile + l16 * D + 32 + quad * 8);

  const __bf16* kt_bh = ktb + (size_t)bh * L * D;
  const size_t row_base = (size_t)bh * L * L + (size_t)(qt * QT) * L;
  const int nbase = wv << 8;  // this wave's s-chunk base

  // ---- phase 1: S = q@k * scale + prev; write scores; keep in regs ----
  f32x4 p[16];
  #pragma unroll
  for (int nt = 0; nt < 16; ++nt) {
    const int n0 = nbase + nt * 16;
    const __bf16* krow = kt_bh + (size_t)(n0 + l16) * D + quad * 8;
    const bf16x8 b0 = *(const bf16x8*)(krow);
    const bf16x8 b1 = *(const bf16x8*)(krow + 32);
    f32x4 c = {0.f, 0.f, 0.f, 0.f};
    c = __builtin_amdgcn_mfma_f32_16x16x32_bf16(a0, b0, c, 0, 0, 0);
    c = __builtin_amdgcn_mfma_f32_16x16x32_bf16(a1, b1, c, 0, 0, 0);
    #pragma unroll
    for (int j = 0; j < 4; ++j) {
      // C layout: row = quad*4+j (q-row), col = l16 (s)
      const size_t off = row_base + (size_t)(quad * 4 + j) * L + (n0 + l16);
      const float sc = c[j] * scale + __builtin_nontemporal_load(&prev[off]);
      __builtin_nontemporal_store(sc, &out_s[off]);
      c[j] = sc;
    }
    p[nt] = c;
  }

  // ---- phase 2: row softmax over full s=1024 ----
  float rm[4];
  #pragma unroll
  for (int j = 0; j < 4; ++j) {
    float m = p[0][j];
    #pragma unroll
    for (int nt = 1; nt < 16; ++nt) m = fmaxf(m, p[nt][j]);
    rm[j] = m;
  }
  #pragma unroll
  for (int sh = 1; sh < 16; sh <<= 1) {
    #pragma unroll
    for (int j = 0; j < 4; ++j) rm[j] = fmaxf(rm[j], __shfl_xor(rm[j], sh, 64));
  }
  if (l16 == 0) {
    #pragma unroll
    for (int j = 0; j < 4; ++j) red_m[wv][quad * 4 + j] = rm[j];
  }
  __syncthreads();
  #pragma unroll
  for (int j = 0; j < 4; ++j) {
    const int qr = quad * 4 + j;
    rm[j] = fmaxf(fmaxf(red_m[0][qr], red_m[1][qr]),
                  fmaxf(red_m[2][qr], red_m[3][qr]));
  }

  float rs[4] = {0.f, 0.f, 0.f, 0.f};
  #pragma unroll
  for (int nt = 0; nt < 16; ++nt) {
    #pragma unroll
    for (int j = 0; j < 4; ++j) {
      const float e = __expf(p[nt][j] - rm[j]);
      p[nt][j] = e;
      rs[j] += e;
    }
  }
  #pragma unroll
  for (int sh = 1; sh < 16; sh <<= 1) {
    #pragma unroll
    for (int j = 0; j < 4; ++j) rs[j] += __shfl_xor(rs[j], sh, 64);
  }
  if (l16 == 0) {
    #pragma unroll
    for (int j = 0; j < 4; ++j) red_s[wv][quad * 4 + j] = rs[j];
  }
  __syncthreads();
  #pragma unroll
  for (int j = 0; j < 4; ++j) {
    const int qr = quad * 4 + j;
    rs[j] = 1.0f / (red_s[0][qr] + red_s[1][qr] + red_s[2][qr] + red_s[3][qr]);
  }

  // ---- weights: write fp32 + stage bf16 into wave-private LDS ----
  __bf16* wl = w_stage + wv * (16 * 280);
  #pragma unroll
  for (int nt = 0; nt < 16; ++nt) {
    #pragma unroll
    for (int j = 0; j < 4; ++j) {
      const int qr = quad * 4 + j;
      const float wt = p[nt][j] * rs[j];
      const size_t off = row_base + (size_t)qr * L + (nbase + nt * 16 + l16);
      __builtin_nontemporal_store(wt, &out_w[off]);
      wl[qr * 280 + nt * 16 + l16] = (__bf16)wt;
    }
  }
  // wave-private LDS region: no block barrier needed before own-wave reads

  // ---- phase 3: O_partial = P_chunk @ V_chunk via MFMA ----
  const __bf16* vt_bh = vtb + (size_t)bh * D * L;
  f32x4 o[4];
  #pragma unroll
  for (int nt = 0; nt < 4; ++nt) o[nt] = (f32x4){0.f, 0.f, 0.f, 0.f};
  #pragma unroll
  for (int ks = 0; ks < 8; ++ks) {
    const bf16x8 aw = *(const bf16x8*)(wl + l16 * 280 + ks * 32 + quad * 8);
    #pragma unroll
    for (int nt = 0; nt < 4; ++nt) {
      const __bf16* vrow =
          vt_bh + (size_t)(nt * 16 + l16) * L + (nbase + ks * 32 + quad * 8);
      const bf16x8 bv = *(const bf16x8*)vrow;
      o[nt] = __builtin_amdgcn_mfma_f32_16x16x32_bf16(aw, bv, o[nt], 0, 0, 0);
    }
  }

  // ---- cross-wave O reduction (o_red aliases w_stage) ----
  __syncthreads();  // everyone done reading w_stage
  #pragma unroll
  for (int nt = 0; nt < 4; ++nt) {
    #pragma unroll
    for (int j = 0; j < 4; ++j)
      o_red[wv * 1024 + (quad * 4 + j) * 64 + nt * 16 + l16] = o[nt][j];
  }
  __syncthreads();
  const size_t obase = (size_t)bh * L * D + (size_t)(qt * QT) * D;
  #pragma unroll
  for (int i = 0; i < 4; ++i) {
    const int idx = i * 256 + tid;
    const float sum =
        o_red[idx] + o_red[1024 + idx] + o_red[2048 + idx] + o_red[3072 + idx];
    out_o[obase + idx] = sum;
  }
}

// ---------------------------------------------------------------------------
extern "C" void kernel_launch(void* const* d_in, const int* in_sizes, int n_in,
                              void* d_out, int out_size, void* d_ws,
                              size_t ws_size, hipStream_t stream)
{
  const float* q     = (const float*)d_in[0];
  const float* k     = (const float*)d_in[1];
  const float* v     = (const float*)d_in[2];
  const float* prev  = (const float*)d_in[3];
  const float* scale = (const float*)d_in[4];

  float* out_o = (float*)d_out;                  // [32][1024][64]
  float* out_w = out_o + (size_t)BH * L * D;     // [32][1024][1024]
  float* out_s = out_w + (size_t)BH * L * L;     // [32][1024][1024]

  __bf16* qb  = (__bf16*)d_ws;                   // 4 MB
  __bf16* ktb = qb + (size_t)BH * L * D;         // 4 MB ([bh][s][d])
  __bf16* vtb = ktb + (size_t)BH * L * D;        // 4 MB ([bh][d][s])

  prep_kernel<<<1280, 256, 0, stream>>>(q, k, v, qb, ktb, vtb);
  attn_kernel<<<2048, 256, 0, stream>>>(qb, ktb, vtb, prev, scale,
                                        out_o, out_w, out_s);
}

// Round 2
// 452.181 us; speedup vs baseline: 1.1603x; 1.1603x over previous
//
#include <hip/hip_runtime.h>
#include <hip/hip_bf16.h>

#define BH 32      // bs*h
#define L  1024    // qlen == slen
#define D  64      // head dim
#define QT 16      // q rows per block

typedef __bf16 bf16x8 __attribute__((ext_vector_type(8)));
typedef float  f32x4  __attribute__((ext_vector_type(4)));

// ---------------------------------------------------------------------------
// Prep: q -> bf16 (same layout); k [bh][d][s] -> ktb [bh][s][d] bf16;
//       v [bh][s][d] -> vtb [bh][d][s] bf16.
// blocks 0..1023: q convert; 1024..1279: k transpose (128-s chunks);
// 1280..1535: v transpose (128-s chunks)
// ---------------------------------------------------------------------------
__global__ __launch_bounds__(256) void prep_kernel(
    const float* __restrict__ q, const float* __restrict__ k,
    const float* __restrict__ v,
    __bf16* __restrict__ qb, __bf16* __restrict__ ktb, __bf16* __restrict__ vtb)
{
  __shared__ __align__(16) __bf16 T[128 * 66];  // 16.9 KB (k view [128s][66])
                                                // v view: [64d][130s] = 16.6 KB
  const int tid = threadIdx.x;
  const int b = blockIdx.x;

  if (b < 1024) {
    // q convert: 8 contiguous elements per thread
    const size_t g = (size_t)b * 256 + tid;
    const float4* qin = (const float4*)q;
    float4 f0 = qin[g * 2];
    float4 f1 = qin[g * 2 + 1];
    union { bf16x8 v8; uint4 u4; } o;
    o.v8[0] = (__bf16)f0.x; o.v8[1] = (__bf16)f0.y;
    o.v8[2] = (__bf16)f0.z; o.v8[3] = (__bf16)f0.w;
    o.v8[4] = (__bf16)f1.x; o.v8[5] = (__bf16)f1.y;
    o.v8[6] = (__bf16)f1.z; o.v8[7] = (__bf16)f1.w;
    *(uint4*)(qb + g * 8) = o.u4;
  } else if (b < 1280) {
    // k transpose: [d][s] -> [s][d], 128-s chunk per block
    const int bb = b - 1024;
    const int bh = bb >> 3, chunk = bb & 7;
    const int s0 = chunk << 7;
    const float* kin = k + (size_t)bh * D * L;
    #pragma unroll
    for (int i = 0; i < 32; ++i) {          // coalesced reads along s
      const int e = i * 256 + tid;
      const int d = e >> 7, s = e & 127;
      T[s * 66 + d] = (__bf16)kin[(size_t)d * L + s0 + s];
    }
    __syncthreads();
    unsigned int* outw = (unsigned int*)ktb;
    const size_t obase = ((size_t)bh * L * D + (size_t)s0 * D) >> 1;  // dword idx
    #pragma unroll
    for (int i = 0; i < 16; ++i) {          // fully coalesced contiguous writes
      const int e = i * 256 + tid;
      const int s = e >> 5, dp = e & 31;
      outw[obase + e] = *(const unsigned int*)&T[s * 66 + dp * 2];
    }
  } else {
    // v transpose: [s][d] -> [d][s], 128-s chunk per block
    const int bb = b - 1280;
    const int bh = bb >> 3, chunk = bb & 7;
    const int s0 = chunk << 7;
    const float* vin = v + (size_t)bh * L * D + (size_t)s0 * D;
    #pragma unroll
    for (int i = 0; i < 32; ++i) {          // coalesced reads
      const int e = i * 256 + tid;
      const int s = e >> 6, d = e & 63;
      T[d * 130 + s] = (__bf16)vin[e];
    }
    __syncthreads();
    unsigned int* outw = (unsigned int*)vtb;
    #pragma unroll
    for (int i = 0; i < 16; ++i) {
      const int e = i * 256 + tid;
      const int d = e >> 6, sp = e & 63;
      outw[(size_t)bh * (L * D / 2) + (size_t)d * (L / 2) + (s0 >> 1) + sp] =
          *(const unsigned int*)&T[d * 130 + sp * 2];
    }
  }
}

// ---------------------------------------------------------------------------
// Main fused kernel: one block per (bh, 16-q-row tile); 4 waves, each owns a
// 256-wide s-chunk. All 64 prev loads per wave are issued up-front (pinned by
// sched_barrier) so each wave keeps ~64 HBM loads in flight; MFMA overlaps
// via TLP (16 waves/CU).
// ---------------------------------------------------------------------------
__global__ __launch_bounds__(256, 4) void attn_kernel(
    const __bf16* __restrict__ qb, const __bf16* __restrict__ ktb,
    const __bf16* __restrict__ vtb,
    const float* __restrict__ prev, const float* __restrict__ scale_p,
    float* __restrict__ out_o, float* __restrict__ out_w,
    float* __restrict__ out_s)
{
  // P-stage: per wave [16 rows][280 cols] bf16; aliased with the O cross-wave
  // reduction buffer (16 KB) -- separated by __syncthreads.
  __shared__ __align__(16) char smem[4 * 16 * 280 * 2];  // 35840 B
  __shared__ float red_m[4][16];
  __shared__ float red_s[4][16];
  __bf16* w_stage = (__bf16*)smem;
  float*  o_red   = (float*)smem;

  const int tid  = threadIdx.x;
  const int wv   = tid >> 6;
  const int lane = tid & 63;
  const int quad = lane >> 4;
  const int l16  = lane & 15;
  const int bh   = blockIdx.x >> 6;
  const int qt   = blockIdx.x & 63;
  const float scale = scale_p[0];

  // A fragments (q tile rows), read straight from global (L2-hot)
  const __bf16* qtile = qb + ((size_t)bh * L + qt * QT) * D;
  const bf16x8 a0 = *(const bf16x8*)(qtile + l16 * D + quad * 8);
  const bf16x8 a1 = *(const bf16x8*)(qtile + l16 * D + 32 + quad * 8);

  const __bf16* kt_bh = ktb + (size_t)bh * L * D;
  const size_t row_base = (size_t)bh * L * L + (size_t)(qt * QT) * L;
  const int nbase = wv << 8;  // this wave's s-chunk base

  // ---- phase 1a: issue ALL prev loads (64 per thread in flight) ----
  f32x4 p[16];
  const float* prow = prev + row_base + (size_t)(quad * 4) * L + nbase + l16;
  #pragma unroll
  for (int nt = 0; nt < 16; ++nt) {
    #pragma unroll
    for (int j = 0; j < 4; ++j)
      p[nt][j] = __builtin_nontemporal_load(prow + (size_t)j * L + nt * 16);
  }
  __builtin_amdgcn_sched_barrier(0);  // don't sink the loads into the MFMA loop

  // ---- phase 1b: S = q@k * scale + prev; write scores; keep in regs ----
  #pragma unroll
  for (int nt = 0; nt < 16; ++nt) {
    const int n0 = nbase + nt * 16;
    const __bf16* krow = kt_bh + (size_t)(n0 + l16) * D + quad * 8;
    const bf16x8 b0 = *(const bf16x8*)(krow);
    const bf16x8 b1 = *(const bf16x8*)(krow + 32);
    f32x4 c = {0.f, 0.f, 0.f, 0.f};
    c = __builtin_amdgcn_mfma_f32_16x16x32_bf16(a0, b0, c, 0, 0, 0);
    c = __builtin_amdgcn_mfma_f32_16x16x32_bf16(a1, b1, c, 0, 0, 0);
    #pragma unroll
    for (int j = 0; j < 4; ++j) {
      // C layout: row = quad*4+j (q-row), col = l16 (s)
      const size_t off = row_base + (size_t)(quad * 4 + j) * L + (n0 + l16);
      const float sc = c[j] * scale + p[nt][j];
      __builtin_nontemporal_store(sc, &out_s[off]);
      p[nt][j] = sc;
    }
  }

  // ---- phase 2: row softmax over full s=1024 ----
  float rm[4];
  #pragma unroll
  for (int j = 0; j < 4; ++j) {
    float m = p[0][j];
    #pragma unroll
    for (int nt = 1; nt < 16; ++nt) m = fmaxf(m, p[nt][j]);
    rm[j] = m;
  }
  #pragma unroll
  for (int sh = 1; sh < 16; sh <<= 1) {
    #pragma unroll
    for (int j = 0; j < 4; ++j) rm[j] = fmaxf(rm[j], __shfl_xor(rm[j], sh, 64));
  }
  if (l16 == 0) {
    #pragma unroll
    for (int j = 0; j < 4; ++j) red_m[wv][quad * 4 + j] = rm[j];
  }
  __syncthreads();
  #pragma unroll
  for (int j = 0; j < 4; ++j) {
    const int qr = quad * 4 + j;
    rm[j] = fmaxf(fmaxf(red_m[0][qr], red_m[1][qr]),
                  fmaxf(red_m[2][qr], red_m[3][qr]));
  }

  float rs[4] = {0.f, 0.f, 0.f, 0.f};
  #pragma unroll
  for (int nt = 0; nt < 16; ++nt) {
    #pragma unroll
    for (int j = 0; j < 4; ++j) {
      const float e = __expf(p[nt][j] - rm[j]);
      p[nt][j] = e;
      rs[j] += e;
    }
  }
  #pragma unroll
  for (int sh = 1; sh < 16; sh <<= 1) {
    #pragma unroll
    for (int j = 0; j < 4; ++j) rs[j] += __shfl_xor(rs[j], sh, 64);
  }
  if (l16 == 0) {
    #pragma unroll
    for (int j = 0; j < 4; ++j) red_s[wv][quad * 4 + j] = rs[j];
  }
  __syncthreads();
  #pragma unroll
  for (int j = 0; j < 4; ++j) {
    const int qr = quad * 4 + j;
    rs[j] = 1.0f / (red_s[0][qr] + red_s[1][qr] + red_s[2][qr] + red_s[3][qr]);
  }

  // ---- weights: write fp32 + stage bf16 into wave-private LDS ----
  __bf16* wl = w_stage + wv * (16 * 280);
  #pragma unroll
  for (int nt = 0; nt < 16; ++nt) {
    #pragma unroll
    for (int j = 0; j < 4; ++j) {
      const int qr = quad * 4 + j;
      const float wt = p[nt][j] * rs[j];
      const size_t off = row_base + (size_t)qr * L + (nbase + nt * 16 + l16);
      __builtin_nontemporal_store(wt, &out_w[off]);
      wl[qr * 280 + nt * 16 + l16] = (__bf16)wt;
    }
  }
  // wave-private LDS region: no block barrier needed before own-wave reads

  // ---- phase 3: O_partial = P_chunk @ V_chunk via MFMA ----
  const __bf16* vt_bh = vtb + (size_t)bh * D * L;
  f32x4 o[4];
  #pragma unroll
  for (int nt = 0; nt < 4; ++nt) o[nt] = (f32x4){0.f, 0.f, 0.f, 0.f};
  #pragma unroll
  for (int ks = 0; ks < 8; ++ks) {
    const bf16x8 aw = *(const bf16x8*)(wl + l16 * 280 + ks * 32 + quad * 8);
    #pragma unroll
    for (int nt = 0; nt < 4; ++nt) {
      const __bf16* vrow =
          vt_bh + (size_t)(nt * 16 + l16) * L + (nbase + ks * 32 + quad * 8);
      const bf16x8 bv = *(const bf16x8*)vrow;
      o[nt] = __builtin_amdgcn_mfma_f32_16x16x32_bf16(aw, bv, o[nt], 0, 0, 0);
    }
  }

  // ---- cross-wave O reduction (o_red aliases w_stage) ----
  __syncthreads();  // everyone done reading w_stage
  #pragma unroll
  for (int nt = 0; nt < 4; ++nt) {
    #pragma unroll
    for (int j = 0; j < 4; ++j)
      o_red[wv * 1024 + (quad * 4 + j) * 64 + nt * 16 + l16] = o[nt][j];
  }
  __syncthreads();
  const size_t obase = (size_t)bh * L * D + (size_t)(qt * QT) * D;
  #pragma unroll
  for (int i = 0; i < 4; ++i) {
    const int idx = i * 256 + tid;
    const float sum =
        o_red[idx] + o_red[1024 + idx] + o_red[2048 + idx] + o_red[3072 + idx];
    out_o[obase + idx] = sum;
  }
}

// ---------------------------------------------------------------------------
extern "C" void kernel_launch(void* const* d_in, const int* in_sizes, int n_in,
                              void* d_out, int out_size, void* d_ws,
                              size_t ws_size, hipStream_t stream)
{
  const float* q     = (const float*)d_in[0];
  const float* k     = (const float*)d_in[1];
  const float* v     = (const float*)d_in[2];
  const float* prev  = (const float*)d_in[3];
  const float* scale = (const float*)d_in[4];

  float* out_o = (float*)d_out;                  // [32][1024][64]
  float* out_w = out_o + (size_t)BH * L * D;     // [32][1024][1024]
  float* out_s = out_w + (size_t)BH * L * L;     // [32][1024][1024]

  __bf16* qb  = (__bf16*)d_ws;                   // 4 MB
  __bf16* ktb = qb + (size_t)BH * L * D;         // 4 MB ([bh][s][d])
  __bf16* vtb = ktb + (size_t)BH * L * D;        // 4 MB ([bh][d][s])

  prep_kernel<<<1536, 256, 0, stream>>>(q, k, v, qb, ktb, vtb);
  attn_kernel<<<2048, 256, 0, stream>>>(qb, ktb, vtb, prev, scale,
                                        out_o, out_w, out_s);
}